// Round 1
// baseline (523.123 us; speedup 1.0000x reference)
//
#include <hip/hip_runtime.h>

// Log-sparse attention, B=4 H=8 L=4096 E=64, fp32.
// One wave (64 lanes) per query row. Keys per query: causal window
// [i-win, i] plus power-of-2 distances > win  (win=32 -> <= 39 keys < 64).
// Lane kk owns score kk; softmax done with cross-lane butterflies.

constexpr int Lq = 4096;   // sequence length (fixed by problem)
constexpr int Ed = 64;     // head dim == wavefront size

__global__ __launch_bounds__(256) void logsparse_attn(
    const float* __restrict__ q,
    const float* __restrict__ k,
    const float* __restrict__ v,
    float* __restrict__ out,
    const int* __restrict__ win_ptr)
{
    const int win_len = *win_ptr;

    const int gtid = blockIdx.x * blockDim.x + threadIdx.x;
    const int wave = gtid >> 6;          // global wave id == query id
    const int lane = threadIdx.x & 63;
    const int i  = wave & (Lq - 1);      // query position
    const int bh = wave >> 12;           // batch*head index (L = 2^12)

    const size_t base = (size_t)bh * Lq * Ed;
    const float* krow = k + base;
    const float* vrow = v + base;

    // q element for this lane, scale folded in (1/sqrt(64) = 0.125)
    const float qv = q[base + (size_t)i * Ed + lane] * 0.125f;

    int w0 = i - win_len; if (w0 < 0) w0 = 0;

    // ---- scores: lane kk keeps score of key kk ----
    float my_s = -1e30f;
    int kk = 0;
    const float* kp = krow + (size_t)w0 * Ed + lane;
    for (int j = w0; j <= i; ++j, ++kk, kp += Ed) {
        float s = qv * (*kp);
        #pragma unroll
        for (int off = 32; off; off >>= 1) s += __shfl_xor(s, off, 64);
        if (lane == kk) my_s = s;
    }
    for (int d = 1; d <= i; d <<= 1) {
        if (d <= win_len) continue;          // already in window
        const int j = i - d;
        float s = qv * krow[(size_t)j * Ed + lane];
        #pragma unroll
        for (int off = 32; off; off >>= 1) s += __shfl_xor(s, off, 64);
        if (lane == kk) my_s = s;
        ++kk;
    }
    const int nkeys = kk;   // wave-uniform, <= 39 for win_len=32

    // ---- softmax across lanes 0..nkeys-1 ----
    float m = my_s;
    #pragma unroll
    for (int off = 32; off; off >>= 1) m = fmaxf(m, __shfl_xor(m, off, 64));
    float p = __expf(my_s - m);
    if (lane >= nkeys) p = 0.0f;             // kill unused lanes exactly
    float denom = p;
    #pragma unroll
    for (int off = 32; off; off >>= 1) denom += __shfl_xor(denom, off, 64);
    p /= denom;

    // ---- PV: lane holds output element `lane` ----
    float acc = 0.0f;
    kk = 0;
    const float* vp = vrow + (size_t)w0 * Ed + lane;
    for (int j = w0; j <= i; ++j, ++kk, vp += Ed) {
        const float pj = __shfl(p, kk, 64);
        acc = fmaf(pj, *vp, acc);
    }
    for (int d = 1; d <= i; d <<= 1) {
        if (d <= win_len) continue;
        const int j = i - d;
        const float pj = __shfl(p, kk, 64);
        acc = fmaf(pj, vrow[(size_t)j * Ed + lane], acc);
        ++kk;
    }

    out[base + (size_t)i * Ed + lane] = acc;
}

extern "C" void kernel_launch(void* const* d_in, const int* in_sizes, int n_in,
                              void* d_out, int out_size, void* d_ws, size_t ws_size,
                              hipStream_t stream) {
    const float* q = (const float*)d_in[0];
    const float* k = (const float*)d_in[1];
    const float* v = (const float*)d_in[2];
    const int* win = (const int*)d_in[3];
    float* out = (float*)d_out;

    const int n_rows = in_sizes[0] / Ed;   // B*H*L query rows
    const int blocks = n_rows / 4;         // 4 waves (queries) per 256-thr block
    logsparse_attn<<<blocks, 256, 0, stream>>>(q, k, v, out, win);
}